// Round 6
// baseline (206.874 us; speedup 1.0000x reference)
//
#include <hip/hip_runtime.h>
#include <math.h>

// CTC forward (keras ctc_batch_cost), B=1024 T=256 C=128 L=64, S=129.
// R6: two-pass split.
//  K1 (BW-shaped, 64 waves/CU): stream y_pred coalesced, gather each lane's
//     label column in-register via ds_bpermute, pack q=(p+eps)*128 to bf16
//     (RNE), write compact ws[b][chunk][entry][8t] (33 KB per batch, 35 MB
//     total). Kills the 128KB-slab lockstep camping + per-row scatter that
//     capped R2/R4/R5 at ~2.3 GB/s per wave.
//  K2 (1 wave64 per batch): burst 33x global_load_lds (whole 33KB sequence)
//     into LDS, two vmcnt waits total; recurrence runs entirely from LDS
//     (2x ds_read_b128 per 8-step chunk). Probability-domain semiring with
//     x128 bias + renorm every 8 steps (validated absmax 0 in R2-R5).

#define Bn 1024
#define Tn 256
#define Cn 128
#define Ln 64
#define BLANK 127
#define U 8
#define NCH (Tn / U)          // 32 chunks
#define ENT 66                // 64 labels + blank + pad
#define CB (ENT * U * 2)      // 1056 bytes per (b, chunk)
#define WSB (NCH * CB)        // 33792 bytes per b
#define NLOAD (WSB / 1024)    // 33 dma16 loads
#define EPS128 (1e-7f * 128.0f)
#define LN2 0.69314718055994530942f

#define WAIT_VM(n) __builtin_amdgcn_s_waitcnt((((n) & 0xF) | (((n) >> 4) << 14)) | 0x0F70)
#define SCHED_FENCE() __builtin_amdgcn_sched_barrier(0)

template <int CTRL>
__device__ __forceinline__ float dpp_movf(float x) {
    return __int_as_float(__builtin_amdgcn_update_dpp(
        0, __float_as_int(x), CTRL, 0xF, 0xF, true));
}
__device__ __forceinline__ int dpp_shr1_i(int x) {
    return __builtin_amdgcn_update_dpp(0, x, 0x138, 0xF, 0xF, true);
}
__device__ __forceinline__ void dma16(const void* g, void* l) {
    __builtin_amdgcn_global_load_lds(
        (const __attribute__((address_space(1))) void*)g,
        (__attribute__((address_space(3))) void*)l, 16, 0, 0);
}

// ---------------- K1: gather + pack ----------------
__global__ __launch_bounds__(256)
void ctc_pack_kernel(const int* __restrict__ yt,
                     const float* __restrict__ yp,
                     unsigned int* __restrict__ ws) {
    const int b = blockIdx.y;
    const int s = blockIdx.x;              // 0..3 (64-row slab)
    const int w = threadIdx.x >> 6;        // wave 0..3
    const int i = threadIdx.x & 63;

    const int li    = yt[b * Ln + i];
    const int baddr = (li >> 1) << 2;      // bpermute: source lane li>>1
    const int sel   = li & 1;

    const float2* rows = (const float2*)(yp + (size_t)b * (Tn * Cn)
                                         + (size_t)(s * 64 + w * 16) * Cn);
    float2 r[16];
#pragma unroll
    for (int t = 0; t < 16; ++t) r[t] = rows[t * (Cn / 2) + i];

    unsigned qdw[2][4], bdw[2][4];
#pragma unroll
    for (int h = 0; h < 2; ++h)
#pragma unroll
        for (int k = 0; k < 4; ++k) { qdw[h][k] = 0u; bdw[h][k] = 0u; }

#pragma unroll
    for (int t = 0; t < 16; ++t) {
        const float q0 = fmaf(r[t].x, 128.0f, EPS128);   // cols 2i, 2i+1
        const float q1 = fmaf(r[t].y, 128.0f, EPS128);
        const unsigned u0 = __float_as_uint(q0), u1 = __float_as_uint(q1);
        const unsigned c0 = (u0 + 0x7FFFu + ((u0 >> 16) & 1u)) >> 16;  // bf16 RNE
        const unsigned c1 = (u1 + 0x7FFFu + ((u1 >> 16) & 1u)) >> 16;
        const unsigned pk = c0 | (c1 << 16);
        const unsigned g  = (unsigned)__builtin_amdgcn_ds_bpermute(baddr, (int)pk);
        const unsigned val = sel ? (g >> 16) : (g & 0xFFFFu);
        const unsigned blk = ((unsigned)__builtin_amdgcn_readlane((int)pk, 63)) >> 16;
        const int h = t >> 3, k = (t & 7) >> 1, sh = (t & 1) << 4;
        qdw[h][k] |= val << sh;
        bdw[h][k] |= blk << sh;
    }

    const int c0i = s * 8 + w * 2;
#pragma unroll
    for (int h = 0; h < 2; ++h) {
        unsigned int* base = ws + ((size_t)b * WSB + (size_t)(c0i + h) * CB) / 4;
        *(uint4*)(base + i * 4) =
            make_uint4(qdw[h][0], qdw[h][1], qdw[h][2], qdw[h][3]);
        if (i == 0)
            *(uint4*)(base + 64 * 4) =
                make_uint4(bdw[h][0], bdw[h][1], bdw[h][2], bdw[h][3]);
    }
}

// ---------------- K2: LDS-resident recurrence ----------------
__global__ __launch_bounds__(64)
void ctc_rec_kernel(const int* __restrict__ yt,
                    const unsigned int* __restrict__ ws,
                    float* __restrict__ out) {
    __shared__ __align__(16) unsigned int lds[WSB / 4];   // 33 KB

    const int b = blockIdx.x;
    const int i = threadIdx.x;

    const int li = yt[b * Ln + i];
    const int ll = dpp_shr1_i(li);
    const float skf = (li != ll) ? 1.0f : 0.0f;

    const char* wsb = (const char*)(ws) + (size_t)b * WSB;
#pragma unroll
    for (int k = 0; k < NLOAD; ++k)
        dma16(wsb + k * 1024 + i * 16, (char*)lds + k * 1024);

    float qlA[U], qbA[U], qlB[U], qbB[U];
    auto qread = [&](int c, float* ql, float* qb) {
        const uint4 vq = *(const uint4*)((const char*)lds + c * CB + i * 16);
        const uint4 vb = *(const uint4*)((const char*)lds + c * CB + 1024);
        const unsigned q[4] = {vq.x, vq.y, vq.z, vq.w};
        const unsigned bq[4] = {vb.x, vb.y, vb.z, vb.w};
#pragma unroll
        for (int k = 0; k < 4; ++k) {
            ql[2 * k]     = __uint_as_float(q[k] << 16);
            ql[2 * k + 1] = __uint_as_float(q[k] & 0xFFFF0000u);
            qb[2 * k]     = __uint_as_float(bq[k] << 16);
            qb[2 * k + 1] = __uint_as_float(bq[k] & 0xFFFF0000u);
        }
    };

    float E = 0.f, O = 0.f, X = 0.f;
    int Esum = 0;

    auto steps = [&](const float* ql, const float* qb, bool first) {
#pragma unroll
        for (int j = 0; j < U; ++j) {
            if (first && j == 0) {
                E = (i == 0) ? qb[0] : 0.f;
                O = (i == 0) ? ql[0] : 0.f;
                X = 0.f;
                continue;
            }
            const float Ol = dpp_movf<0x138>(O);
            const float t1 = O + E;
            const float nO = fmaf(skf, Ol, t1) * ql[j];
            const float nE = (E + Ol) * qb[j];
            const float nX = (X + O) * qb[j];
            E = nE; O = nO; X = nX;
        }
    };
    auto renorm = [&]() {
        float m = fmaxf(E, O);
        if (i == 63) m = fmaxf(m, X);
        m = fmaxf(m, dpp_movf<0x111>(m));
        m = fmaxf(m, dpp_movf<0x112>(m));
        m = fmaxf(m, dpp_movf<0x114>(m));
        m = fmaxf(m, dpp_movf<0x118>(m));
        m = fmaxf(m, dpp_movf<0x142>(m));
        m = fmaxf(m, dpp_movf<0x143>(m));
        const unsigned ub =
            (unsigned)__builtin_amdgcn_readlane(__float_as_int(m), 63);
        const int eb = (int)(ub >> 23);
        const float sc = __int_as_float((unsigned)(254 - eb) << 23);
        Esum += eb - 127;
        E *= sc; O *= sc; X *= sc;
    };

    WAIT_VM(16); SCHED_FENCE();            // 17 loads landed -> chunks 0..15
    qread(0, qlA, qbA);
    for (int cc = 0; cc < 14; cc += 2) {
        qread(cc + 1, qlB, qbB); steps(qlA, qbA, cc == 0); renorm();
        qread(cc + 2, qlA, qbA); steps(qlB, qbB, false);   renorm();
    }
    qread(15, qlB, qbB); steps(qlA, qbA, false); renorm();   // chunk 14
    WAIT_VM(0); SCHED_FENCE();             // all 33 landed
    qread(16, qlA, qbA); steps(qlB, qbB, false); renorm();   // chunk 15
    for (int cc = 16; cc < 30; cc += 2) {
        qread(cc + 1, qlB, qbB); steps(qlA, qbA, false); renorm();
        qread(cc + 2, qlA, qbA); steps(qlB, qbB, false); renorm();
    }
    qread(31, qlB, qbB); steps(qlA, qbA, false); renorm();   // chunk 30
    steps(qlB, qbB, false);                                  // chunk 31

    if (i == 63) {
        const float s = O + X;
#if __has_builtin(__builtin_amdgcn_logf)
        const float l2 = __builtin_amdgcn_logf(s);
#else
        const float l2 = log2f(s);
#endif
        out[b] = -(l2 + (float)(Esum - 7 * Tn)) * LN2;
    }
}

extern "C" void kernel_launch(void* const* d_in, const int* in_sizes, int n_in,
                              void* d_out, int out_size, void* d_ws, size_t ws_size,
                              hipStream_t stream) {
    const int*   y_true = (const int*)d_in[0];
    const float* y_pred = (const float*)d_in[1];
    float*       out    = (float*)d_out;
    unsigned int* ws    = (unsigned int*)d_ws;

    hipLaunchKernelGGL(ctc_pack_kernel, dim3(4, Bn), dim3(256), 0, stream,
                       y_true, y_pred, ws);
    hipLaunchKernelGGL(ctc_rec_kernel, dim3(Bn), dim3(64), 0, stream,
                       y_true, ws, out);
}